// Round 4
// baseline (214.925 us; speedup 1.0000x reference)
//
#include <hip/hip_runtime.h>
#include <math.h>

// DigitCaps dynamic routing, MI355X. Round 11: quarter-batch tasks +
// route-parity lane split (fix round-10's 2x block imbalance).
//
// Round-10 post-mortem: lane=batch structure was right (VGPR 32, zero
// conflicts, no shuffles) but grid=332 blocks over 256 CUs -> 76 CUs carry
// two 8-wave blocks (2x work of the rest) and average residency was only
// ~1.6 waves/SIMD (OccupancyPercent 19.9) -> per-route W-load latency
// (~200cy L2) unhidden, VALUBusy stuck at 49%, dur 98.5us ~= 2x balanced
// ideal. Aggregate VALU issue is only ~17-20us: pure balance/latency
// problem.
//
// Round 11:
//  - task = (j, 32-batch quarter): 664 blocks (= 8*83, exact XCD swizzle),
//    8 waves each -> 5312 waves ~ 20.8/CU (5.2/SIMD), imbalance 1.16x.
//  - lane = (route-parity g, b32): wave w owns routes [w*108, (w+1)*108);
//    lane handles r = w*108 + 2*step + g, step<54. The 32 lanes of a half
//    read the SAME W address (HW broadcast); parities share one 128B line.
//  - g-merge: one shfl_xor(32) per reduced float; then 8-wave LDS combine
//    (lanes<32), 2 barriers/iteration, 6 total.
//  - W via VMEM now (per-lane addresses differ across halves); W[j] 54KB
//    L2-hot via swizzle. u pre-transposed fp16 uT[r][b]: two 256B segments
//    per wave load.
//  - math identical to round 10 (u_hat f32, fdot2, fp32 softmax) ->
//    absmax unchanged.

#define BB 128
#define JJ 166
#define RR 864
#define OO 8
#define W_U2 (JJ * RR * 8)  // W fp16: (j*864+r)*8 uint2 = 64 B per route

typedef __fp16 h2v __attribute__((ext_vector_type(2)));
typedef float f32x2 __attribute__((ext_vector_type(2)));

static __device__ __forceinline__ uint32_t pack2(float a, float b) {
    return __builtin_bit_cast(uint32_t, __builtin_amdgcn_cvt_pkrtz(a, b));
}
static __device__ __forceinline__ h2v bc_h2(uint32_t u) {
    return __builtin_bit_cast(h2v, u);
}

// ---- pre-pass: W -> fp16 [j][r][8 o-pairs]; u -> fp16 uT[r][b] ----
__global__ __launch_bounds__(256) void prepack_kernel(
    const float* __restrict__ u, const float* __restrict__ W,
    uint2* __restrict__ ws) {
    const int t = blockIdx.x * 256 + threadIdx.x;
    if (t < JJ * RR) {
        // one (j,r): read 8 float4 (128 B), write 8 uint2 (64 B)
        const float4* __restrict__ W4 = (const float4*)W + (size_t)t * 8;
        uint2* __restrict__ dst = ws + (size_t)t * 8;
#pragma unroll
        for (int o = 0; o < 8; ++o) {
            const float4 wv = W4[o];
            dst[o] = make_uint2(pack2(wv.x, wv.y), pack2(wv.z, wv.w));
        }
    } else {
        const int e = t - JJ * RR;  // e = r*128 + b (coalesced writes)
        if (e < RR * BB) {
            const int r = e >> 7;
            const int b = e & 127;
            const float4 uu = ((const float4*)u)[(size_t)b * RR + r];
            ws[W_U2 + e] = make_uint2(pack2(uu.x, uu.y), pack2(uu.z, uu.w));
        }
    }
}

// 16 fdot2: d2[k].x = o=2k, d2[k].y = o=2k+1 (w0..w3, up in scope)
#define UHAT(D)                                                                \
    {                                                                          \
        float p;                                                               \
        p = __builtin_amdgcn_fdot2(bc_h2(w0.x), bc_h2(up.x), 0.0f, false);     \
        D[0].x = __builtin_amdgcn_fdot2(bc_h2(w0.y), bc_h2(up.y), p, false);   \
        p = __builtin_amdgcn_fdot2(bc_h2(w0.z), bc_h2(up.x), 0.0f, false);     \
        D[0].y = __builtin_amdgcn_fdot2(bc_h2(w0.w), bc_h2(up.y), p, false);   \
        p = __builtin_amdgcn_fdot2(bc_h2(w1.x), bc_h2(up.x), 0.0f, false);     \
        D[1].x = __builtin_amdgcn_fdot2(bc_h2(w1.y), bc_h2(up.y), p, false);   \
        p = __builtin_amdgcn_fdot2(bc_h2(w1.z), bc_h2(up.x), 0.0f, false);     \
        D[1].y = __builtin_amdgcn_fdot2(bc_h2(w1.w), bc_h2(up.y), p, false);   \
        p = __builtin_amdgcn_fdot2(bc_h2(w2.x), bc_h2(up.x), 0.0f, false);     \
        D[2].x = __builtin_amdgcn_fdot2(bc_h2(w2.y), bc_h2(up.y), p, false);   \
        p = __builtin_amdgcn_fdot2(bc_h2(w2.z), bc_h2(up.x), 0.0f, false);     \
        D[2].y = __builtin_amdgcn_fdot2(bc_h2(w2.w), bc_h2(up.y), p, false);   \
        p = __builtin_amdgcn_fdot2(bc_h2(w3.x), bc_h2(up.x), 0.0f, false);     \
        D[3].x = __builtin_amdgcn_fdot2(bc_h2(w3.y), bc_h2(up.y), p, false);   \
        p = __builtin_amdgcn_fdot2(bc_h2(w3.z), bc_h2(up.x), 0.0f, false);     \
        D[3].y = __builtin_amdgcn_fdot2(bc_h2(w3.w), bc_h2(up.y), p, false);   \
    }

#define LOAD_W(T)                                                              \
    const uint4 w0 = *(const uint4*)(Wr + (T) * 32);                           \
    const uint4 w1 = *(const uint4*)(Wr + (T) * 32 + 4);                       \
    const uint4 w2 = *(const uint4*)(Wr + (T) * 32 + 8);                       \
    const uint4 w3 = *(const uint4*)(Wr + (T) * 32 + 12);

// merge route-parity halves: each lane adds its xor-32 partner's partial
#define GMERGE(x) x += __shfl_xor(x, 32, 64)

__global__ __launch_bounds__(512) void digitcaps_kernel(
    const uint32_t* __restrict__ Wp,  // [(j*864+r)*16] dwords, 64 B per route
    const uint2* __restrict__ uT,     // [r*128 + b]
    float* __restrict__ out) {
    const int tid = threadIdx.x;
    const int l = tid & 63;
    const int w = tid >> 6;   // wave: route chunk [w*108, (w+1)*108)
    const int g = l >> 5;     // route parity within chunk
    const int b32 = l & 31;

    // XCD swizzle: 664 = 8*83 exact. 4 consecutive bids share j -> same XCD.
    const int orig = blockIdx.x;
    const int bid = (orig & 7) * 83 + (orig >> 3);
    const int j = bid >> 2;
    const int bq = bid & 3;
    const int b = (bq << 5) + b32;

    const int r0 = w * 108 + g;  // lane's routes: r0 + 2*step, step < 54
    const uint32_t* __restrict__ Wr = Wp + ((size_t)j * RR + r0) * 16;
    const uint2* __restrict__ ur = uT + (size_t)r0 * BB + b;

    // cross-wave combine scratch: 8 wave-partials x 32 b-lanes
    __shared__ float4 xA[8 * 32];  // s[0..3]
    __shared__ float4 xB[8 * 32];  // s[4..7]
    __shared__ float xZ[8 * 32];   // z
    // total LDS: 8*32*36 = 9,216 B

    f32x2 V2[4], v2[4];

    // ---- iteration 0: c uniform = 1/R -> s = (sum_r u_hat)/R ----
    {
        f32x2 s2[4];
#pragma unroll
        for (int k = 0; k < 4; ++k) { s2[k].x = 0.f; s2[k].y = 0.f; }
#pragma unroll 2
        for (int t = 0; t < 54; ++t) {
            const uint2 up = ur[t * 2 * BB];
            LOAD_W(t)
            f32x2 d2[4];
            UHAT(d2)
#pragma unroll
            for (int k = 0; k < 4; ++k) s2[k] += d2[k];
        }
#pragma unroll
        for (int k = 0; k < 4; ++k) { GMERGE(s2[k].x); GMERGE(s2[k].y); }
        if (g == 0) {
            xA[w * 32 + b32] = make_float4(s2[0].x, s2[0].y, s2[1].x, s2[1].y);
            xB[w * 32 + b32] = make_float4(s2[2].x, s2[2].y, s2[3].x, s2[3].y);
        }
        __syncthreads();
        float4 A = xA[b32], B = xB[b32];
#pragma unroll
        for (int w2i = 1; w2i < 8; ++w2i) {
            const float4 a2 = xA[w2i * 32 + b32], b2 = xB[w2i * 32 + b32];
            A.x += a2.x; A.y += a2.y; A.z += a2.z; A.w += a2.w;
            B.x += b2.x; B.y += b2.y; B.z += b2.z; B.w += b2.w;
        }
        __syncthreads();
        const float inv = 1.0f / (float)RR;
        f32x2 sc[4];
        sc[0].x = A.x * inv; sc[0].y = A.y * inv;
        sc[1].x = A.z * inv; sc[1].y = A.w * inv;
        sc[2].x = B.x * inv; sc[2].y = B.y * inv;
        sc[3].x = B.z * inv; sc[3].y = B.w * inv;
        float n2 = 0.f;
#pragma unroll
        for (int k = 0; k < 4; ++k) n2 += sc[k].x * sc[k].x + sc[k].y * sc[k].y;
        const float scale = sqrtf(n2) / (1.0f + n2);
#pragma unroll
        for (int k = 0; k < 4; ++k) { v2[k] = sc[k] * scale; V2[k] = v2[k]; }
    }

    // ---- iterations 1 and 2 ----
#pragma unroll
    for (int it = 1; it < 3; ++it) {
        f32x2 sz2[4];
        float z = 0.f;
#pragma unroll
        for (int k = 0; k < 4; ++k) { sz2[k].x = 0.f; sz2[k].y = 0.f; }
#pragma unroll 2
        for (int t = 0; t < 54; ++t) {
            const uint2 up = ur[t * 2 * BB];
            LOAD_W(t)
            f32x2 d2[4];
            UHAT(d2)
            // logit b_r = <u_hat, V> (V = running sum of past v's)
            f32x2 lac = d2[0] * V2[0];
            lac += d2[1] * V2[1];
            lac += d2[2] * V2[2];
            lac += d2[3] * V2[3];
            const float br = lac.x + lac.y;
            const float e = __expf(br);
            z += e;
            f32x2 e2; e2.x = e; e2.y = e;
#pragma unroll
            for (int k = 0; k < 4; ++k) sz2[k] += e2 * d2[k];
        }
#pragma unroll
        for (int k = 0; k < 4; ++k) { GMERGE(sz2[k].x); GMERGE(sz2[k].y); }
        GMERGE(z);
        if (g == 0) {
            xA[w * 32 + b32] = make_float4(sz2[0].x, sz2[0].y, sz2[1].x, sz2[1].y);
            xB[w * 32 + b32] = make_float4(sz2[2].x, sz2[2].y, sz2[3].x, sz2[3].y);
            xZ[w * 32 + b32] = z;
        }
        __syncthreads();
        float4 A = xA[b32], B = xB[b32];
        float Z = xZ[b32];
#pragma unroll
        for (int w2i = 1; w2i < 8; ++w2i) {
            const float4 a2 = xA[w2i * 32 + b32], b2 = xB[w2i * 32 + b32];
            A.x += a2.x; A.y += a2.y; A.z += a2.z; A.w += a2.w;
            B.x += b2.x; B.y += b2.y; B.z += b2.z; B.w += b2.w;
            Z += xZ[w2i * 32 + b32];
        }
        __syncthreads();
        const float invZ = 1.0f / Z;
        f32x2 sc[4];
        sc[0].x = A.x * invZ; sc[0].y = A.y * invZ;
        sc[1].x = A.z * invZ; sc[1].y = A.w * invZ;
        sc[2].x = B.x * invZ; sc[2].y = B.y * invZ;
        sc[3].x = B.z * invZ; sc[3].y = B.w * invZ;
        float n2 = 0.f;
#pragma unroll
        for (int k = 0; k < 4; ++k) n2 += sc[k].x * sc[k].x + sc[k].y * sc[k].y;
        const float scale = sqrtf(n2) / (1.0f + n2);
#pragma unroll
        for (int k = 0; k < 4; ++k) v2[k] = sc[k] * scale;
        if (it == 1) {
#pragma unroll
            for (int k = 0; k < 4; ++k) V2[k] += v2[k];
        }
    }

    // ---- write out[b][j][0..7]; wave 0, lanes g==0 (one lane per b) ----
    if (w == 0 && g == 0) {
        float4* dst = (float4*)(out + ((size_t)b * JJ + j) * OO);
        dst[0] = make_float4(v2[0].x, v2[0].y, v2[1].x, v2[1].y);
        dst[1] = make_float4(v2[2].x, v2[2].y, v2[3].x, v2[3].y);
    }
}

extern "C" void kernel_launch(void* const* d_in, const int* in_sizes, int n_in,
                              void* d_out, int out_size, void* d_ws, size_t ws_size,
                              hipStream_t stream) {
    const float* u = (const float*)d_in[0];  // [128, 864, 4]
    const float* W = (const float*)d_in[1];  // [1, 166, 864, 8, 4]
    float* out = (float*)d_out;              // [128, 166, 8]
    uint2* ws = (uint2*)d_ws;                // needs 10.07 MB

    // pre-pass: 166*864 W-routes + 864*128 u-elements, one thread each
    const int total = JJ * RR + RR * BB;
    prepack_kernel<<<(total + 255) / 256, 256, 0, stream>>>(u, W, ws);

    // main: 166 j x 4 b-quarters, 512 threads = 8 waves x (2 parities x 32 b)
    digitcaps_kernel<<<JJ * 4, 512, 0, stream>>>(
        (const uint32_t*)ws, ((const uint2*)ws) + W_U2, out);
}

// Round 5
// 131.481 us; speedup vs baseline: 1.6347x; 1.6347x over previous
//
#include <hip/hip_runtime.h>
#include <math.h>

// DigitCaps dynamic routing, MI355X. Round 12: back to the R8 champion core
// (prepacked fp16 W -> global_load_lds -> LDS; fp16 u_hat cached in regs;
// per-wave routing) + occupancy and reduction-latency fixes.
//
// Cross-round invariant: VALUBusy*dur ~= 46-53us in every structure tried
// (R7 53, R8 46, R10 48, R11 51) -> VALU issue volume is constant; dur is
// set by utilization (best 58%). R9/R10/R11 restructures all regressed.
// R8's utilization sinks: ~7.3 waves/CU resident, and 26 six-deep
// shfl_xor (ds_bpermute ~35cy/hop) reduction chains per wave.
//
// Round 12:
//  - 4-wave 256-thread blocks, 7 uniform chunks of 128 routes (896-padded):
//    LDS 2x8KB=16KB -> residency cap ~6 blocks = 24 waves/CU (R8: 32KB,
//    measured 7.3 waves/CU). Grid 5312 = 8*664 exact XCD swizzle.
//  - DPP wave reductions: row_shr 1/2/4/8 + row_bcast15/31 + readlane(63)
//    -> 6 low-latency VALU adds per sum, result in SGPR (free broadcast),
//    replacing 6 ds_bpermute hops per sum (26 sums/wave).
//  - Compute core, pipeline (stage c+1 || compute c, 1 barrier/phase),
//    masks, numerics identical to R8 -> absmax unchanged.

#define BB 128
#define JJ 166
#define RR 864
#define OO 8
#define KMAX 14            // 14 k-slots of 64 routes; k=13 lanes>=32 are pad
#define WP_U2 (JJ * 7168)  // W fp16: per j: 7 chunks * 1024 uint2 = 57,344 B
#define UP_U2 (BB * 896)   // u fp16: [b][896] uint2, routes >=864 zeroed

typedef __fp16 h2v __attribute__((ext_vector_type(2)));

static __device__ __forceinline__ uint32_t pack2(float a, float b) {
    return __builtin_bit_cast(uint32_t, __builtin_amdgcn_cvt_pkrtz(a, b));
}
static __device__ __forceinline__ h2v bc_h2(uint32_t u) {
    return __builtin_bit_cast(h2v, u);
}
static __device__ __forceinline__ float lo_f(uint32_t u) {
    return (float)__builtin_bit_cast(h2v, u).x;
}
static __device__ __forceinline__ float hi_f(uint32_t u) {
    return (float)__builtin_bit_cast(h2v, u).y;
}

// Full-wave (64-lane) sum via DPP cascade; total lands in lane 63, then
// readlane -> SGPR (uniform across the wave). All-lanes-active required.
static __device__ __forceinline__ float dpp_wave_sum(float x) {
#define DPP_STEP(CTRL)                                                         \
    x += __builtin_bit_cast(                                                   \
        float, __builtin_amdgcn_update_dpp(0, __builtin_bit_cast(int, x),      \
                                           (CTRL), 0xF, 0xF, true));
    DPP_STEP(0x111)  // row_shr:1
    DPP_STEP(0x112)  // row_shr:2
    DPP_STEP(0x114)  // row_shr:4
    DPP_STEP(0x118)  // row_shr:8  -> lane15/31/47/63 hold row sums
    DPP_STEP(0x142)  // row_bcast:15 -> lane31 = sum(0..31), lane63 = sum(32..63)
    DPP_STEP(0x143)  // row_bcast:31 -> lane63 = total
#undef DPP_STEP
    return __builtin_bit_cast(
        float, __builtin_amdgcn_readlane(__builtin_bit_cast(int, x), 63));
}

// ---- pre-pass: W -> fp16 Wp[j][c7][o8][rl128]; u -> fp16 uT[b][896] ----
__global__ __launch_bounds__(256) void prepack_kernel(
    const float* __restrict__ u, const float* __restrict__ W,
    uint2* __restrict__ ws) {
    const int t = threadIdx.x;
    const int bid = blockIdx.x;
    if (bid < JJ * 7) {
        const int j = bid / 7;
        const int c = bid - j * 7;
        const float4* __restrict__ W4 = (const float4*)W;  // [(j*864+r)*8+o]
        uint2* __restrict__ dst = ws + (size_t)bid * 1024;
#pragma unroll
        for (int i = 0; i < 4; ++i) {
            const int e = i * 256 + t;   // [o][rl]
            const int o = e >> 7;
            const int rl = e & 127;
            const int r = c * 128 + rl;
            float4 w = make_float4(0.f, 0.f, 0.f, 0.f);
            if (r < RR) w = W4[((size_t)j * RR + r) * 8 + o];
            dst[e] = make_uint2(pack2(w.x, w.y), pack2(w.z, w.w));
        }
    } else {
        // u pack: e in [0, 128*896)
        const int e = (bid - JJ * 7) * 256 + t;
        const int b = e / 896;
        const int r = e - b * 896;
        const float4* __restrict__ u4 = (const float4*)u;
        float4 uu = make_float4(0.f, 0.f, 0.f, 0.f);
        if (r < RR) uu = u4[(size_t)b * RR + r];
        ws[WP_U2 + e] = make_uint2(pack2(uu.x, uu.y), pack2(uu.z, uu.w));
    }
}

__global__ __launch_bounds__(256) void digitcaps_kernel(
    const uint2* __restrict__ Wp, const uint2* __restrict__ uP,
    float* __restrict__ out) {
    const int tid = threadIdx.x;
    const int lane = tid & 63;
    const int wave = tid >> 6;

    // XCD-bijective swizzle: 5312 blocks = 8 XCDs x 664. The 32 same-j
    // blocks become consecutive on one XCD -> Wp[j] (56 KB) L2-hot.
    int bid = blockIdx.x;
    bid = (bid & 7) * 664 + (bid >> 3);
    const int j = bid >> 5;
    const int b = ((bid & 31) << 2) + wave;

    // two W buffers, each one 128-route chunk [o][rl] uint2: 16,384 B total
    __shared__ uint2 wlds[2][1024];

    const uint2* __restrict__ uPb = uP + (size_t)b * 896;

    uint32_t uh[KMAX][4];  // u_hat packed fp16 pairs; constant-indexed only

    // ---- stage chunk CC into LDS buffer BUF via async global->LDS ----
#define STAGE(CC, BUF)                                                         \
    {                                                                          \
        const char* gsrc = (const char*)(Wp + ((size_t)j * 7 + (CC)) * 1024);  \
        _Pragma("unroll")                                                      \
        for (int i = 0; i < 2; ++i) {                                          \
            __builtin_amdgcn_global_load_lds(                                  \
                (const __attribute__((address_space(1))) uint32_t*)            \
                    (gsrc + i * 4096 + tid * 16),                              \
                (__attribute__((address_space(3))) uint32_t*)                  \
                    ((char*)(&wlds[BUF][0]) + i * 4096 + (wave << 10)),        \
                16, 0, 0);                                                     \
        }                                                                      \
    }

    // ---- u_hat for chunk CC: 2 k-slots (zero-padding kills all guards) ----
#define COMPUTE(CC, BUF)                                                       \
    {                                                                          \
        _Pragma("unroll")                                                      \
        for (int kl = 0; kl < 2; ++kl) {                                       \
            const int rl = (kl << 6) + lane;                                   \
            const uint2 up = uPb[(CC) * 128 + rl];                             \
            float d[OO];                                                       \
            _Pragma("unroll")                                                  \
            for (int o = 0; o < OO; ++o) {                                     \
                const uint2 ww = wlds[BUF][o * 128 + rl];                      \
                float t0 = __builtin_amdgcn_fdot2(bc_h2(ww.x), bc_h2(up.x),    \
                                                  0.0f, false);                \
                d[o] = __builtin_amdgcn_fdot2(bc_h2(ww.y), bc_h2(up.y), t0,    \
                                              false);                          \
            }                                                                  \
            _Pragma("unroll")                                                  \
            for (int o2 = 0; o2 < 4; ++o2)                                     \
                uh[(CC) * 2 + kl][o2] = pack2(d[2 * o2], d[2 * o2 + 1]);       \
        }                                                                      \
    }

    STAGE(0, 0)
    __syncthreads();
    STAGE(1, 1) COMPUTE(0, 0)
    __syncthreads();
    STAGE(2, 0) COMPUTE(1, 1)
    __syncthreads();
    STAGE(3, 1) COMPUTE(2, 0)
    __syncthreads();
    STAGE(4, 0) COMPUTE(3, 1)
    __syncthreads();
    STAGE(5, 1) COMPUTE(4, 0)
    __syncthreads();
    STAGE(6, 0) COMPUTE(5, 1)
    __syncthreads();
    COMPUTE(6, 0)
#undef STAGE
#undef COMPUTE

    float V[OO];  // running sum of past v's (b_r = <uhat_r, V>)
    float v[OO];

    // ---- iteration 0: b=0 -> c uniform = 1/R (packed fp16 partial sums) ----
    {
        h2v accp[4];
#pragma unroll
        for (int o2 = 0; o2 < 4; ++o2) accp[o2] = bc_h2(uh[0][o2]);
#pragma unroll
        for (int k = 1; k < KMAX; ++k)
#pragma unroll
            for (int o2 = 0; o2 < 4; ++o2) accp[o2] += bc_h2(uh[k][o2]);

        float s[OO];
#pragma unroll
        for (int o2 = 0; o2 < 4; ++o2) {
            s[2 * o2]     = dpp_wave_sum((float)accp[o2].x) * (1.0f / (float)RR);
            s[2 * o2 + 1] = dpp_wave_sum((float)accp[o2].y) * (1.0f / (float)RR);
        }
        float n2 = 0.0f;
#pragma unroll
        for (int o = 0; o < OO; ++o) n2 += s[o] * s[o];
        const float scale = sqrtf(n2) / (1.0f + n2);
#pragma unroll
        for (int o = 0; o < OO; ++o) { v[o] = s[o] * scale; V[o] = v[o]; }
    }

    // ---- iterations 1 and 2 ----
#pragma unroll
    for (int it = 1; it < 3; ++it) {
        // pack V once per iteration for dot2 logits
        uint32_t Vp[4];
#pragma unroll
        for (int o2 = 0; o2 < 4; ++o2)
            Vp[o2] = pack2(V[2 * o2], V[2 * o2 + 1]);

        float zp = 0.0f;
        float sp[OO];
#pragma unroll
        for (int o = 0; o < OO; ++o) sp[o] = 0.0f;

#pragma unroll
        for (int k = 0; k < KMAX; ++k) {
            float br = 0.0f;
#pragma unroll
            for (int o2 = 0; o2 < 4; ++o2)
                br = __builtin_amdgcn_fdot2(bc_h2(uh[k][o2]), bc_h2(Vp[o2]),
                                            br, false);
            // mask pad routes (k==13, lane>=32): exp(0)=1 would pollute Z
            const float e = (k < KMAX - 1 || lane < 32) ? __expf(br) : 0.0f;
            zp += e;
#pragma unroll
            for (int o2 = 0; o2 < 4; ++o2) {
                sp[2 * o2]     = fmaf(e, lo_f(uh[k][o2]), sp[2 * o2]);
                sp[2 * o2 + 1] = fmaf(e, hi_f(uh[k][o2]), sp[2 * o2 + 1]);
            }
        }
        const float invZ = 1.0f / dpp_wave_sum(zp);

        float s[OO];
#pragma unroll
        for (int o = 0; o < OO; ++o) s[o] = dpp_wave_sum(sp[o]) * invZ;

        float n2 = 0.0f;
#pragma unroll
        for (int o = 0; o < OO; ++o) n2 += s[o] * s[o];
        const float scale = sqrtf(n2) / (1.0f + n2);
#pragma unroll
        for (int o = 0; o < OO; ++o) v[o] = s[o] * scale;

        if (it < 2) {
#pragma unroll
            for (int o = 0; o < OO; ++o) V[o] += v[o];
        }
    }

    // ---- write out[b][j][o]; v uniform across lanes (SGPR sums) ----
    float outv = 0.0f;
#pragma unroll
    for (int o = 0; o < OO; ++o)
        if (lane == o) outv = v[o];
    if (lane < OO) out[(b * JJ + j) * OO + lane] = outv;
}

extern "C" void kernel_launch(void* const* d_in, const int* in_sizes, int n_in,
                              void* d_out, int out_size, void* d_ws, size_t ws_size,
                              hipStream_t stream) {
    const float* u = (const float*)d_in[0];  // [128, 864, 4]
    const float* W = (const float*)d_in[1];  // [1, 166, 864, 8, 4]
    float* out = (float*)d_out;              // [128, 166, 8]
    uint2* ws = (uint2*)d_ws;                // needs (WP_U2 + UP_U2)*8 ~= 10.3 MB

    // pre-pass: 166*7 W-chunk blocks + 448 u blocks
    prepack_kernel<<<JJ * 7 + (BB * 896) / 256, 256, 0, stream>>>(u, W, ws);

    // main: 166 j * 32 b-groups, 256 threads = 4 waves = 4 b's
    digitcaps_kernel<<<JJ * 32, 256, 0, stream>>>(ws, ws + WP_U2, out);
}

// Round 6
// 124.886 us; speedup vs baseline: 1.7210x; 1.0528x over previous
//
#include <hip/hip_runtime.h>
#include <math.h>

// DigitCaps dynamic routing, MI355X. Round 13: R12 champion + ds_read_b128
// paired-o LDS layout + 4-buffer staging (7 -> 4 barriers).
//
// R12 post-mortem (93.7 -> 67.5us, VALUBusy 70%): DPP sums + 16KB LDS +
// uniform chunks worked as predicted. Remaining: VALUBusy*dur ~= 47us
// VALU-volume invariant + 30% idle. Identified overhead: 112 ds_read_b64
// per wave in the u_hat phase (issue slots) and 7 barrier drains.
//
// Round 13:
//  - W prepacked per chunk as [op 0..3][rl 0..127][p 0..1] uint2 so each
//    k-slot reads 4 x ds_read_b128 (two o's per read) instead of 8 x b64.
//    global_load_lds stays linear-dest; the permutation is in the global
//    prepack (swizzle-the-source pattern).
//  - 4 LDS buffers (32 KB), stage schedule with 4 barriers:
//    {S0 S1 S2 | S3 C0 C1 | S4 S5 C2 C3 | S6 C4 C5 | C6}; each buffer's
//    re-stage is barrier-separated from its last read; compute phases hold
//    2 chunks (4 independent u-loads) for VMEM overlap.
//  - DPP wave reductions, fp16 uh cache, masks, numerics identical to R12
//    -> absmax unchanged.

#define BB 128
#define JJ 166
#define RR 864
#define OO 8
#define KMAX 14            // 14 k-slots of 64 routes; k=13 lanes>=32 are pad
#define WP_U2 (JJ * 7168)  // W fp16: per j: 7 chunks * 1024 uint2 = 57,344 B
#define UP_U2 (BB * 896)   // u fp16: [b][896] uint2, routes >=864 zeroed

typedef __fp16 h2v __attribute__((ext_vector_type(2)));

static __device__ __forceinline__ uint32_t pack2(float a, float b) {
    return __builtin_bit_cast(uint32_t, __builtin_amdgcn_cvt_pkrtz(a, b));
}
static __device__ __forceinline__ h2v bc_h2(uint32_t u) {
    return __builtin_bit_cast(h2v, u);
}
static __device__ __forceinline__ float lo_f(uint32_t u) {
    return (float)__builtin_bit_cast(h2v, u).x;
}
static __device__ __forceinline__ float hi_f(uint32_t u) {
    return (float)__builtin_bit_cast(h2v, u).y;
}

// Full-wave (64-lane) sum via DPP cascade; total lands in lane 63, then
// readlane -> SGPR (uniform across the wave). All-lanes-active required.
static __device__ __forceinline__ float dpp_wave_sum(float x) {
#define DPP_STEP(CTRL)                                                         \
    x += __builtin_bit_cast(                                                   \
        float, __builtin_amdgcn_update_dpp(0, __builtin_bit_cast(int, x),      \
                                           (CTRL), 0xF, 0xF, true));
    DPP_STEP(0x111)  // row_shr:1
    DPP_STEP(0x112)  // row_shr:2
    DPP_STEP(0x114)  // row_shr:4
    DPP_STEP(0x118)  // row_shr:8  -> lane15/31/47/63 hold row sums
    DPP_STEP(0x142)  // row_bcast:15 -> lane31 = sum(0..31), lane63 = sum(32..63)
    DPP_STEP(0x143)  // row_bcast:31 -> lane63 = total
#undef DPP_STEP
    return __builtin_bit_cast(
        float, __builtin_amdgcn_readlane(__builtin_bit_cast(int, x), 63));
}

// ---- pre-pass: W -> fp16 Wp[j][c7][op4][rl128][p2]; u -> fp16 uT[b][896] ----
__global__ __launch_bounds__(256) void prepack_kernel(
    const float* __restrict__ u, const float* __restrict__ W,
    uint2* __restrict__ ws) {
    const int t = threadIdx.x;
    const int bid = blockIdx.x;
    if (bid < JJ * 7) {
        const int j = bid / 7;
        const int c = bid - j * 7;
        const float4* __restrict__ W4 = (const float4*)W;  // [(j*864+r)*8+o]
        uint2* __restrict__ dst = ws + (size_t)bid * 1024;
#pragma unroll
        for (int i = 0; i < 4; ++i) {
            const int e = i * 256 + t;   // e = op*256 + rl*2 + p
            const int op = e >> 8;
            const int rl = (e & 255) >> 1;
            const int p = e & 1;
            const int o = 2 * op + p;
            const int r = c * 128 + rl;
            float4 w = make_float4(0.f, 0.f, 0.f, 0.f);
            if (r < RR) w = W4[((size_t)j * RR + r) * 8 + o];
            dst[e] = make_uint2(pack2(w.x, w.y), pack2(w.z, w.w));
        }
    } else {
        // u pack: e in [0, 128*896)
        const int e = (bid - JJ * 7) * 256 + t;
        const int b = e / 896;
        const int r = e - b * 896;
        const float4* __restrict__ u4 = (const float4*)u;
        float4 uu = make_float4(0.f, 0.f, 0.f, 0.f);
        if (r < RR) uu = u4[(size_t)b * RR + r];
        ws[WP_U2 + e] = make_uint2(pack2(uu.x, uu.y), pack2(uu.z, uu.w));
    }
}

__global__ __launch_bounds__(256) void digitcaps_kernel(
    const uint2* __restrict__ Wp, const uint2* __restrict__ uP,
    float* __restrict__ out) {
    const int tid = threadIdx.x;
    const int lane = tid & 63;
    const int wave = tid >> 6;

    // XCD-bijective swizzle: 5312 blocks = 8 XCDs x 664. The 32 same-j
    // blocks become consecutive on one XCD -> Wp[j] (56 KB) L2-hot.
    int bid = blockIdx.x;
    bid = (bid & 7) * 664 + (bid >> 3);
    const int j = bid >> 5;
    const int b = ((bid & 31) << 2) + wave;

    // four W buffers, each one 128-route chunk [op][rl][p] uint2: 32,768 B
    __shared__ uint2 wlds[4][1024];

    const uint2* __restrict__ uPb = uP + (size_t)b * 896;

    uint32_t uh[KMAX][4];  // u_hat packed fp16 pairs; constant-indexed only

    // ---- stage chunk CC into LDS buffer BUF via async global->LDS ----
#define STAGE(CC, BUF)                                                         \
    {                                                                          \
        const char* gsrc = (const char*)(Wp + ((size_t)j * 7 + (CC)) * 1024);  \
        _Pragma("unroll")                                                      \
        for (int i = 0; i < 2; ++i) {                                          \
            __builtin_amdgcn_global_load_lds(                                  \
                (const __attribute__((address_space(1))) uint32_t*)            \
                    (gsrc + i * 4096 + tid * 16),                              \
                (__attribute__((address_space(3))) uint32_t*)                  \
                    ((char*)(&wlds[BUF][0]) + i * 4096 + (wave << 10)),        \
                16, 0, 0);                                                     \
        }                                                                      \
    }

    // ---- u_hat for chunk CC: 2 k-slots, 4 x ds_read_b128 per slot ----
#define COMPUTE(CC, BUF)                                                       \
    {                                                                          \
        _Pragma("unroll")                                                      \
        for (int kl = 0; kl < 2; ++kl) {                                       \
            const int rl = (kl << 6) + lane;                                   \
            const uint2 up = uPb[(CC) * 128 + rl];                             \
            _Pragma("unroll")                                                  \
            for (int op = 0; op < 4; ++op) {                                   \
                const uint4 ww =                                               \
                    *(const uint4*)(&wlds[BUF][op * 256 + (rl << 1)]);         \
                float t0 = __builtin_amdgcn_fdot2(bc_h2(ww.x), bc_h2(up.x),    \
                                                  0.0f, false);                \
                const float d0 = __builtin_amdgcn_fdot2(bc_h2(ww.y),           \
                                                        bc_h2(up.y), t0,      \
                                                        false);               \
                float t1 = __builtin_amdgcn_fdot2(bc_h2(ww.z), bc_h2(up.x),    \
                                                  0.0f, false);                \
                const float d1 = __builtin_amdgcn_fdot2(bc_h2(ww.w),           \
                                                        bc_h2(up.y), t1,      \
                                                        false);               \
                uh[(CC) * 2 + kl][op] = pack2(d0, d1);                         \
            }                                                                  \
        }                                                                      \
    }

    // 4-buffer schedule; each buffer's re-stage barrier-separated from its
    // last read: {S0 S1 S2 | S3 C0 C1 | S4 S5 C2 C3 | S6 C4 C5 | C6}
    STAGE(0, 0) STAGE(1, 1) STAGE(2, 2)
    __syncthreads();
    STAGE(3, 3) COMPUTE(0, 0) COMPUTE(1, 1)
    __syncthreads();
    STAGE(4, 0) STAGE(5, 1) COMPUTE(2, 2) COMPUTE(3, 3)
    __syncthreads();
    STAGE(6, 2) COMPUTE(4, 0) COMPUTE(5, 1)
    __syncthreads();
    COMPUTE(6, 2)
#undef STAGE
#undef COMPUTE

    float V[OO];  // running sum of past v's (b_r = <uhat_r, V>)
    float v[OO];

    // ---- iteration 0: b=0 -> c uniform = 1/R (packed fp16 partial sums) ----
    {
        h2v accp[4];
#pragma unroll
        for (int o2 = 0; o2 < 4; ++o2) accp[o2] = bc_h2(uh[0][o2]);
#pragma unroll
        for (int k = 1; k < KMAX; ++k)
#pragma unroll
            for (int o2 = 0; o2 < 4; ++o2) accp[o2] += bc_h2(uh[k][o2]);

        float s[OO];
#pragma unroll
        for (int o2 = 0; o2 < 4; ++o2) {
            s[2 * o2]     = dpp_wave_sum((float)accp[o2].x) * (1.0f / (float)RR);
            s[2 * o2 + 1] = dpp_wave_sum((float)accp[o2].y) * (1.0f / (float)RR);
        }
        float n2 = 0.0f;
#pragma unroll
        for (int o = 0; o < OO; ++o) n2 += s[o] * s[o];
        const float scale = sqrtf(n2) / (1.0f + n2);
#pragma unroll
        for (int o = 0; o < OO; ++o) { v[o] = s[o] * scale; V[o] = v[o]; }
    }

    // ---- iterations 1 and 2 ----
#pragma unroll
    for (int it = 1; it < 3; ++it) {
        // pack V once per iteration for dot2 logits
        uint32_t Vp[4];
#pragma unroll
        for (int o2 = 0; o2 < 4; ++o2)
            Vp[o2] = pack2(V[2 * o2], V[2 * o2 + 1]);

        float zp = 0.0f;
        float sp[OO];
#pragma unroll
        for (int o = 0; o < OO; ++o) sp[o] = 0.0f;

#pragma unroll
        for (int k = 0; k < KMAX; ++k) {
            float br = 0.0f;
#pragma unroll
            for (int o2 = 0; o2 < 4; ++o2)
                br = __builtin_amdgcn_fdot2(bc_h2(uh[k][o2]), bc_h2(Vp[o2]),
                                            br, false);
            // mask pad routes (k==13, lane>=32): exp(0)=1 would pollute Z
            const float e = (k < KMAX - 1 || lane < 32) ? __expf(br) : 0.0f;
            zp += e;
#pragma unroll
            for (int o2 = 0; o2 < 4; ++o2) {
                sp[2 * o2]     = fmaf(e, lo_f(uh[k][o2]), sp[2 * o2]);
                sp[2 * o2 + 1] = fmaf(e, hi_f(uh[k][o2]), sp[2 * o2 + 1]);
            }
        }
        const float invZ = 1.0f / dpp_wave_sum(zp);

        float s[OO];
#pragma unroll
        for (int o = 0; o < OO; ++o) s[o] = dpp_wave_sum(sp[o]) * invZ;

        float n2 = 0.0f;
#pragma unroll
        for (int o = 0; o < OO; ++o) n2 += s[o] * s[o];
        const float scale = sqrtf(n2) / (1.0f + n2);
#pragma unroll
        for (int o = 0; o < OO; ++o) v[o] = s[o] * scale;

        if (it < 2) {
#pragma unroll
            for (int o = 0; o < OO; ++o) V[o] += v[o];
        }
    }

    // ---- write out[b][j][o]; v uniform across lanes (SGPR sums) ----
    float outv = 0.0f;
#pragma unroll
    for (int o = 0; o < OO; ++o)
        if (lane == o) outv = v[o];
    if (lane < OO) out[(b * JJ + j) * OO + lane] = outv;
}

extern "C" void kernel_launch(void* const* d_in, const int* in_sizes, int n_in,
                              void* d_out, int out_size, void* d_ws, size_t ws_size,
                              hipStream_t stream) {
    const float* u = (const float*)d_in[0];  // [128, 864, 4]
    const float* W = (const float*)d_in[1];  // [1, 166, 864, 8, 4]
    float* out = (float*)d_out;              // [128, 166, 8]
    uint2* ws = (uint2*)d_ws;                // needs (WP_U2 + UP_U2)*8 ~= 10.3 MB

    // pre-pass: 166*7 W-chunk blocks + 448 u blocks
    prepack_kernel<<<JJ * 7 + (BB * 896) / 256, 256, 0, stream>>>(u, W, ws);

    // main: 166 j * 32 b-groups, 256 threads = 4 waves = 4 b's
    digitcaps_kernel<<<JJ * 32, 256, 0, stream>>>(ws, ws + WP_U2, out);
}

// Round 7
// 123.367 us; speedup vs baseline: 1.7422x; 1.0123x over previous
//
#include <hip/hip_runtime.h>
#include <math.h>

// DigitCaps dynamic routing, MI355X. Round 14: R13 + __launch_bounds__(256,4)
// to stop AGPR-parking of the uh[] cache.
//
// R13 post-mortem (62.4us, VALUBusy 76.5%): VALUBusy*dur invariant held at
// 47.7us (R12 47.3) -> utilization rose, volume didn't. Implied busy
// cycles/wave ~5500 (~2750 VALU instrs) vs ~1200 counted from source.
// Smoking gun: VGPR_Count=48 < live uh[14][4]=56 regs, with zero scratch
// (WRITE_SIZE == output bytes). On gfx950's unified RF the compiler parked
// uh in AGPRs -> v_accvgpr_read/write VALU moves on every uh access
// (~350+/wave) = the phantom volume.
//
// Round 14 (single variable): __launch_bounds__(256, 4) raises the arch-VGPR
// budget to 128/wave (4 waves/SIMD min). uh(56)+working(~35) fits -> no
// accvgpr churn. Occupancy cap 16 waves/CU vs measured ~12 average -> no
// loss. Kernel body identical to R13 -> absmax unchanged.
//
// Carried structure (R12+R13): prepacked fp16 W chunks, global_load_lds
// width=16 linear-dest staging, 4 LDS buffers / 4 barriers, paired-o
// ds_read_b128 layout, DPP wave reductions into SGPRs, fp16 uh cache,
// XCD-bijective swizzle, 896-padded routes (no guards).

#define BB 128
#define JJ 166
#define RR 864
#define OO 8
#define KMAX 14            // 14 k-slots of 64 routes; k=13 lanes>=32 are pad
#define WP_U2 (JJ * 7168)  // W fp16: per j: 7 chunks * 1024 uint2 = 57,344 B
#define UP_U2 (BB * 896)   // u fp16: [b][896] uint2, routes >=864 zeroed

typedef __fp16 h2v __attribute__((ext_vector_type(2)));

static __device__ __forceinline__ uint32_t pack2(float a, float b) {
    return __builtin_bit_cast(uint32_t, __builtin_amdgcn_cvt_pkrtz(a, b));
}
static __device__ __forceinline__ h2v bc_h2(uint32_t u) {
    return __builtin_bit_cast(h2v, u);
}
static __device__ __forceinline__ float lo_f(uint32_t u) {
    return (float)__builtin_bit_cast(h2v, u).x;
}
static __device__ __forceinline__ float hi_f(uint32_t u) {
    return (float)__builtin_bit_cast(h2v, u).y;
}

// Full-wave (64-lane) sum via DPP cascade; total lands in lane 63, then
// readlane -> SGPR (uniform across the wave). All-lanes-active required.
static __device__ __forceinline__ float dpp_wave_sum(float x) {
#define DPP_STEP(CTRL)                                                         \
    x += __builtin_bit_cast(                                                   \
        float, __builtin_amdgcn_update_dpp(0, __builtin_bit_cast(int, x),      \
                                           (CTRL), 0xF, 0xF, true));
    DPP_STEP(0x111)  // row_shr:1
    DPP_STEP(0x112)  // row_shr:2
    DPP_STEP(0x114)  // row_shr:4
    DPP_STEP(0x118)  // row_shr:8  -> lane15/31/47/63 hold row sums
    DPP_STEP(0x142)  // row_bcast:15 -> lane31 = sum(0..31), lane63 = sum(32..63)
    DPP_STEP(0x143)  // row_bcast:31 -> lane63 = total
#undef DPP_STEP
    return __builtin_bit_cast(
        float, __builtin_amdgcn_readlane(__builtin_bit_cast(int, x), 63));
}

// ---- pre-pass: W -> fp16 Wp[j][c7][op4][rl128][p2]; u -> fp16 uT[b][896] ----
__global__ __launch_bounds__(256) void prepack_kernel(
    const float* __restrict__ u, const float* __restrict__ W,
    uint2* __restrict__ ws) {
    const int t = threadIdx.x;
    const int bid = blockIdx.x;
    if (bid < JJ * 7) {
        const int j = bid / 7;
        const int c = bid - j * 7;
        const float4* __restrict__ W4 = (const float4*)W;  // [(j*864+r)*8+o]
        uint2* __restrict__ dst = ws + (size_t)bid * 1024;
#pragma unroll
        for (int i = 0; i < 4; ++i) {
            const int e = i * 256 + t;   // e = op*256 + rl*2 + p
            const int op = e >> 8;
            const int rl = (e & 255) >> 1;
            const int p = e & 1;
            const int o = 2 * op + p;
            const int r = c * 128 + rl;
            float4 w = make_float4(0.f, 0.f, 0.f, 0.f);
            if (r < RR) w = W4[((size_t)j * RR + r) * 8 + o];
            dst[e] = make_uint2(pack2(w.x, w.y), pack2(w.z, w.w));
        }
    } else {
        // u pack: e in [0, 128*896)
        const int e = (bid - JJ * 7) * 256 + t;
        const int b = e / 896;
        const int r = e - b * 896;
        const float4* __restrict__ u4 = (const float4*)u;
        float4 uu = make_float4(0.f, 0.f, 0.f, 0.f);
        if (r < RR) uu = u4[(size_t)b * RR + r];
        ws[WP_U2 + e] = make_uint2(pack2(uu.x, uu.y), pack2(uu.z, uu.w));
    }
}

__global__ __launch_bounds__(256, 4) void digitcaps_kernel(
    const uint2* __restrict__ Wp, const uint2* __restrict__ uP,
    float* __restrict__ out) {
    const int tid = threadIdx.x;
    const int lane = tid & 63;
    const int wave = tid >> 6;

    // XCD-bijective swizzle: 5312 blocks = 8 XCDs x 664. The 32 same-j
    // blocks become consecutive on one XCD -> Wp[j] (56 KB) L2-hot.
    int bid = blockIdx.x;
    bid = (bid & 7) * 664 + (bid >> 3);
    const int j = bid >> 5;
    const int b = ((bid & 31) << 2) + wave;

    // four W buffers, each one 128-route chunk [op][rl][p] uint2: 32,768 B
    __shared__ uint2 wlds[4][1024];

    const uint2* __restrict__ uPb = uP + (size_t)b * 896;

    uint32_t uh[KMAX][4];  // u_hat packed fp16 pairs; constant-indexed only

    // ---- stage chunk CC into LDS buffer BUF via async global->LDS ----
#define STAGE(CC, BUF)                                                         \
    {                                                                          \
        const char* gsrc = (const char*)(Wp + ((size_t)j * 7 + (CC)) * 1024);  \
        _Pragma("unroll")                                                      \
        for (int i = 0; i < 2; ++i) {                                          \
            __builtin_amdgcn_global_load_lds(                                  \
                (const __attribute__((address_space(1))) uint32_t*)            \
                    (gsrc + i * 4096 + tid * 16),                              \
                (__attribute__((address_space(3))) uint32_t*)                  \
                    ((char*)(&wlds[BUF][0]) + i * 4096 + (wave << 10)),        \
                16, 0, 0);                                                     \
        }                                                                      \
    }

    // ---- u_hat for chunk CC: 2 k-slots, 4 x ds_read_b128 per slot ----
#define COMPUTE(CC, BUF)                                                       \
    {                                                                          \
        _Pragma("unroll")                                                      \
        for (int kl = 0; kl < 2; ++kl) {                                       \
            const int rl = (kl << 6) + lane;                                   \
            const uint2 up = uPb[(CC) * 128 + rl];                             \
            _Pragma("unroll")                                                  \
            for (int op = 0; op < 4; ++op) {                                   \
                const uint4 ww =                                               \
                    *(const uint4*)(&wlds[BUF][op * 256 + (rl << 1)]);         \
                float t0 = __builtin_amdgcn_fdot2(bc_h2(ww.x), bc_h2(up.x),    \
                                                  0.0f, false);                \
                const float d0 = __builtin_amdgcn_fdot2(bc_h2(ww.y),           \
                                                        bc_h2(up.y), t0,      \
                                                        false);               \
                float t1 = __builtin_amdgcn_fdot2(bc_h2(ww.z), bc_h2(up.x),    \
                                                  0.0f, false);                \
                const float d1 = __builtin_amdgcn_fdot2(bc_h2(ww.w),           \
                                                        bc_h2(up.y), t1,      \
                                                        false);               \
                uh[(CC) * 2 + kl][op] = pack2(d0, d1);                         \
            }                                                                  \
        }                                                                      \
    }

    // 4-buffer schedule; each buffer's re-stage barrier-separated from its
    // last read: {S0 S1 S2 | S3 C0 C1 | S4 S5 C2 C3 | S6 C4 C5 | C6}
    STAGE(0, 0) STAGE(1, 1) STAGE(2, 2)
    __syncthreads();
    STAGE(3, 3) COMPUTE(0, 0) COMPUTE(1, 1)
    __syncthreads();
    STAGE(4, 0) STAGE(5, 1) COMPUTE(2, 2) COMPUTE(3, 3)
    __syncthreads();
    STAGE(6, 2) COMPUTE(4, 0) COMPUTE(5, 1)
    __syncthreads();
    COMPUTE(6, 2)
#undef STAGE
#undef COMPUTE

    float V[OO];  // running sum of past v's (b_r = <uhat_r, V>)
    float v[OO];

    // ---- iteration 0: b=0 -> c uniform = 1/R (packed fp16 partial sums) ----
    {
        h2v accp[4];
#pragma unroll
        for (int o2 = 0; o2 < 4; ++o2) accp[o2] = bc_h2(uh[0][o2]);
#pragma unroll
        for (int k = 1; k < KMAX; ++k)
#pragma unroll
            for (int o2 = 0; o2 < 4; ++o2) accp[o2] += bc_h2(uh[k][o2]);

        float s[OO];
#pragma unroll
        for (int o2 = 0; o2 < 4; ++o2) {
            s[2 * o2]     = dpp_wave_sum((float)accp[o2].x) * (1.0f / (float)RR);
            s[2 * o2 + 1] = dpp_wave_sum((float)accp[o2].y) * (1.0f / (float)RR);
        }
        float n2 = 0.0f;
#pragma unroll
        for (int o = 0; o < OO; ++o) n2 += s[o] * s[o];
        const float scale = sqrtf(n2) / (1.0f + n2);
#pragma unroll
        for (int o = 0; o < OO; ++o) { v[o] = s[o] * scale; V[o] = v[o]; }
    }

    // ---- iterations 1 and 2 ----
#pragma unroll
    for (int it = 1; it < 3; ++it) {
        // pack V once per iteration for dot2 logits
        uint32_t Vp[4];
#pragma unroll
        for (int o2 = 0; o2 < 4; ++o2)
            Vp[o2] = pack2(V[2 * o2], V[2 * o2 + 1]);

        float zp = 0.0f;
        float sp[OO];
#pragma unroll
        for (int o = 0; o < OO; ++o) sp[o] = 0.0f;

#pragma unroll
        for (int k = 0; k < KMAX; ++k) {
            float br = 0.0f;
#pragma unroll
            for (int o2 = 0; o2 < 4; ++o2)
                br = __builtin_amdgcn_fdot2(bc_h2(uh[k][o2]), bc_h2(Vp[o2]),
                                            br, false);
            // mask pad routes (k==13, lane>=32): exp(0)=1 would pollute Z
            const float e = (k < KMAX - 1 || lane < 32) ? __expf(br) : 0.0f;
            zp += e;
#pragma unroll
            for (int o2 = 0; o2 < 4; ++o2) {
                sp[2 * o2]     = fmaf(e, lo_f(uh[k][o2]), sp[2 * o2]);
                sp[2 * o2 + 1] = fmaf(e, hi_f(uh[k][o2]), sp[2 * o2 + 1]);
            }
        }
        const float invZ = 1.0f / dpp_wave_sum(zp);

        float s[OO];
#pragma unroll
        for (int o = 0; o < OO; ++o) s[o] = dpp_wave_sum(sp[o]) * invZ;

        float n2 = 0.0f;
#pragma unroll
        for (int o = 0; o < OO; ++o) n2 += s[o] * s[o];
        const float scale = sqrtf(n2) / (1.0f + n2);
#pragma unroll
        for (int o = 0; o < OO; ++o) v[o] = s[o] * scale;

        if (it < 2) {
#pragma unroll
            for (int o = 0; o < OO; ++o) V[o] += v[o];
        }
    }

    // ---- write out[b][j][o]; v uniform across lanes (SGPR sums) ----
    float outv = 0.0f;
#pragma unroll
    for (int o = 0; o < OO; ++o)
        if (lane == o) outv = v[o];
    if (lane < OO) out[(b * JJ + j) * OO + lane] = outv;
}

extern "C" void kernel_launch(void* const* d_in, const int* in_sizes, int n_in,
                              void* d_out, int out_size, void* d_ws, size_t ws_size,
                              hipStream_t stream) {
    const float* u = (const float*)d_in[0];  // [128, 864, 4]
    const float* W = (const float*)d_in[1];  // [1, 166, 864, 8, 4]
    float* out = (float*)d_out;              // [128, 166, 8]
    uint2* ws = (uint2*)d_ws;                // needs (WP_U2 + UP_U2)*8 ~= 10.3 MB

    // pre-pass: 166*7 W-chunk blocks + 448 u blocks
    prepack_kernel<<<JJ * 7 + (BB * 896) / 256, 256, 0, stream>>>(u, W, ws);

    // main: 166 j * 32 b-groups, 256 threads = 4 waves = 4 b's
    digitcaps_kernel<<<JJ * 32, 256, 0, stream>>>(ws, ws + WP_U2, out);
}